// Round 10
// baseline (151.942 us; speedup 1.0000x reference)
//
#include <hip/hip_runtime.h>
#include <hip/hip_bf16.h>
#include <math.h>

#define BATCH 4
#define SEQ   4096
#define EMB   1024
#define HD    64
#define SCALE 0.03125f   // EMB^-0.5 = 1/32, exact in bf16
#define NSTRIPE 4

typedef __attribute__((ext_vector_type(8))) short short8;  // 8 bf16 = 4 VGPRs
typedef __attribute__((ext_vector_type(4))) float f32x4;

__device__ __forceinline__ short8 ld8g(const __hip_bfloat16* p) {
    union { uint4 u; short8 s; } cv;
    cv.u = *(const uint4*)p;
    return cv.s;
}
__device__ __forceinline__ short8 ld8l(const void* p) {
    union { uint4 u; short8 s; } cv;
    cv.u = *(const uint4*)p;
    return cv.s;
}
__device__ __forceinline__ unsigned short bfb(float a) {
    union { __hip_bfloat16 h; unsigned short u; } cv;
    cv.h = __hip_bfloat16(a);
    return cv.u;
}

// async global->LDS DMA, 16 B/lane. LDS dest = wave-uniform base + lane*16.
__device__ __forceinline__ void gld16(const void* g, const void* lds_base) {
    __builtin_amdgcn_global_load_lds(
        (const __attribute__((address_space(1))) void*)(unsigned long long)(uintptr_t)g,
        (__attribute__((address_space(3))) void*)(unsigned)(uintptr_t)lds_base,
        16, 0, 0);
}

// ---------------------------------------------------------------------------
// prep_w v2: coalesced transpose via LDS (unchanged, ~2 us).
// ---------------------------------------------------------------------------
__global__ __launch_bounds__(256) void prep_w(
    const float* __restrict__ Wk, const float* __restrict__ Wq,
    const float* __restrict__ Wv, __hip_bfloat16* __restrict__ WT)
{
    __shared__ float ls[64][65];
    const int wsel = blockIdx.x >> 4;
    const int kblk = blockIdx.x & 15;
    const int k0   = kblk * 64;
    const float* W = (wsel == 0) ? Wq : (wsel == 1) ? Wk : Wv;
    const int t = threadIdx.x;
#pragma unroll
    for (int i = 0; i < 4; ++i) {
        const int idx = t + i * 256;
        const int row = idx >> 4;
        const int c4  = idx & 15;
        const float4 v = *(const float4*)(W + (size_t)(k0 + row) * HD + c4 * 4);
        ls[row][c4 * 4 + 0] = v.x; ls[row][c4 * 4 + 1] = v.y;
        ls[row][c4 * 4 + 2] = v.z; ls[row][c4 * 4 + 3] = v.w;
    }
    __syncthreads();
    const int h   = t >> 2;
    const int kk0 = (t & 3) * 16;
#pragma unroll
    for (int i = 0; i < 2; ++i) {
        const int kk = kk0 + i * 8;
        union { unsigned short u[8]; uint4 q; } pk;
#pragma unroll
        for (int j = 0; j < 8; ++j) pk.u[j] = bfb(ls[kk + j][h]);
        *(uint4*)(WT + (size_t)(wsel * 64 + h) * EMB + k0 + kk) = pk.q;
    }
}

// ---------------------------------------------------------------------------
// gemm_proj v6: N split across blocks for TLP + traffic.
// R9 post-mortem: dbuf is defeated (__syncthreads drains vmcnt(0) including
// the prefetch DMA) -> revert to single-buffer. Instead: 1024 blocks x 256
// thr; block = 32 rows x 96 cols (nh half), wave = 16 rows x 48 cols
// (3 frags). LDS 20.8 KB -> ALL 4 blocks/CU co-resident (was 2), B re-read
// halved. Same DMA staging + XOR swizzle as v4 (37.5 us at 2 blocks/CU).
// ---------------------------------------------------------------------------
__global__ __launch_bounds__(256) void gemm_proj(
    const float* __restrict__ x,
    const __hip_bfloat16* __restrict__ WT,
    __hip_bfloat16* __restrict__ qs,
    __hip_bfloat16* __restrict__ kb,
    __hip_bfloat16* __restrict__ vT)
{
    __shared__ __align__(16) char sm[8 * 1040 + 12 * 1040];   // 20,800 B
    char* smA = sm;                     // A: 8 groups x 4 rows
    char* smB = sm + 8 * 1040;          // B: 12 groups x 8 rows

    const int tid  = threadIdx.x;
    const int lane = tid & 63;
    const int c    = lane & 15;
    const int quad = lane >> 4;
    const int w    = tid >> 6;          // 0..3
    const int rw   = w & 1;             // 16-row half
    const int nq   = w >> 1;            // 48-col quarter (within nh half)
    const int mblk = blockIdx.x >> 1;
    const int nh   = blockIdx.x & 1;    // 96-col half
    const int R0   = mblk * 32;
    const int n0   = nh * 96;

    // DMA lane invariants
    const int rrA = lane >> 4;                 // A row-in-group 0..3
    const int ciA = (lane & 15) ^ (rrA << 1);  // stored pos holds chunk ps^(r<<1)
    const int rrB = lane >> 3;                 // B row-in-group 0..7
    const int ciB = (lane & 7) ^ rrB;

    // compute invariants
    const int rA  = rw * 16 + c;        // A row this lane consumes (0..31)
    const int gA  = rA >> 2;
    const int rrr = rA & 3;
    const char* paBase = smA + gA * 1040 + rrr * 256;

    f32x4 acc[3];
#pragma unroll
    for (int f = 0; f < 3; ++f) acc[f] = (f32x4){0.f, 0.f, 0.f, 0.f};

    for (int s = 0; s < 16; ++s) {
        const int k0 = s * 64;

        // ---- stage: 2 A-groups + 3 B-groups per wave (async DMA) ----
#pragma unroll
        for (int j = 0; j < 2; ++j) {
            const int g = w * 2 + j;
            gld16(x + (size_t)(R0 + g * 4 + rrA) * EMB + k0 + ciA * 4,
                  smA + g * 1040);
        }
#pragma unroll
        for (int j = 0; j < 3; ++j) {
            const int gb = w * 3 + j;
            gld16(WT + (size_t)(n0 + gb * 8 + rrB) * EMB + k0 + ciB * 8,
                  smB + gb * 1040);
        }
        __syncthreads();                // drains DMA + barrier

        // ---- compute: 2 K-steps of 32, 3 MFMA each ----
#pragma unroll
        for (int ks = 0; ks < 2; ++ks) {
            const int ci0 = ks * 8 + quad * 2;          // even
            const int ps0 = ci0 ^ (rrr << 1);
            const char* pa = paBase + ps0 * 16;
            const float4 fa = *(const float4*)pa;
            const float4 fb = *(const float4*)(pa + 16);
            union { unsigned short u[8]; short8 s8; } av;
            av.u[0] = bfb(fa.x); av.u[1] = bfb(fa.y);
            av.u[2] = bfb(fa.z); av.u[3] = bfb(fa.w);
            av.u[4] = bfb(fb.x); av.u[5] = bfb(fb.y);
            av.u[6] = bfb(fb.z); av.u[7] = bfb(fb.w);
#pragma unroll
            for (int f = 0; f < 3; ++f) {
                const int nl  = nq * 48 + f * 16 + c;   // local col 0..95
                const int gB  = nl >> 3;
                const int rB  = nl & 7;
                const int psb = (ks * 4 + quad) ^ rB;
                const short8 bfrag = ld8l(smB + gB * 1040 + rB * 128 + psb * 16);
                acc[f] = __builtin_amdgcn_mfma_f32_16x16x32_bf16(av.s8, bfrag, acc[f], 0, 0, 0);
            }
        }
        __syncthreads();                // all reads done before restage
    }

    // ---- epilogue: D[m][n = n0 + nq*48 + f*16 + c] ----
#pragma unroll
    for (int f = 0; f < 3; ++f) {
#pragma unroll
        for (int r = 0; r < 4; ++r) {
            const int m = R0 + rw * 16 + quad * 4 + r;
            const int n = n0 + nq * 48 + f * 16 + c;    // 0..191
            const float val = acc[f][r];
            if (n < 64) {
                qs[(size_t)m * HD + n] = __hip_bfloat16(val * SCALE);
            } else if (n < 128) {
                kb[(size_t)m * HD + (n - 64)] = __hip_bfloat16(val);
            } else {
                const int b  = m >> 12;
                const int sq = m & (SEQ - 1);
                const int sp = (sq & ~63) | ((sq & 15) << 2) | ((sq >> 4) & 3);
                vT[((size_t)b * HD + (n - 128)) * SEQ + sp] = __hip_bfloat16(val);
            }
        }
    }
}

// ---------------------------------------------------------------------------
// attn v5: R9 structure + PER-CU LOAD BALANCE. Grid 1024 = 4 blocks/CU all
// co-resident, and co-resident blocks are {g, g+256, g+512, g+768} (same low
// byte) -> R9's map gave all 4 the SAME t: per-CU work ranged 1..64 tile-
// visits (wall = heaviest CU ~30 us). v5: gen->t bijections with constant
// per-CU sum: {63-r, r, (r+16)&63, 63-((r+16)&63)} -> 126+4 visits per CU,
// uniform. Stripe = gen (max-free softmax => partials additive).
// ---------------------------------------------------------------------------
__global__ __launch_bounds__(256) void attn_kernel(
    const __hip_bfloat16* __restrict__ qs,
    const __hip_bfloat16* __restrict__ kmat,
    const __hip_bfloat16* __restrict__ vT,
    float* __restrict__ Opart,     // [NSTRIPE][BATCH*SEQ*HD]
    float* __restrict__ Lpart)     // [NSTRIPE][BATCH*SEQ]
{
    __shared__ __align__(16) char smK[64 * 128];
    __shared__ __align__(16) char smV[64 * 128];
    __shared__ unsigned int Ps[4][16 * 36];

    const int tid  = threadIdx.x;
    const int w    = tid >> 6;
    const int lane = tid & 63;
    const int c    = lane & 15;
    const int quad = lane >> 4;

    const int g   = blockIdx.x;          // 0..1023
    const int gen = g >> 8;              // generation = stripe
    const int jj  = g & 255;
    const int b   = jj & 3;
    const int r_  = jj >> 2;             // 0..63
    int t;
    if      (gen == 0) t = 63 - r_;
    else if (gen == 1) t = r_;
    else if (gen == 2) t = (r_ + 16) & 63;
    else               t = 63 - ((r_ + 16) & 63);
    const int stripe = gen;
    const int q0w    = t * 64 + w * 16;

    const __hip_bfloat16* kbb = kmat + (size_t)b * SEQ * HD;
    const __hip_bfloat16* vTb = vT + (size_t)b * HD * SEQ;

    const __hip_bfloat16* qp = qs + ((size_t)b * SEQ + q0w + c) * HD + quad * 8;
    const short8 aq0 = ld8g(qp);
    const short8 aq1 = ld8g(qp + 32);

    const int rr = lane >> 3;
    const int ci = (lane & 7) ^ rr;

    f32x4 o0 = {0.f,0.f,0.f,0.f}, o1 = o0, o2 = o0, o3 = o0;
    f32x4 lp = {0.f,0.f,0.f,0.f};
    const f32x4 z = {0.f,0.f,0.f,0.f};

    for (int T = stripe; T <= t; T += NSTRIPE) {
        const int k0 = T << 6;

#pragma unroll
        for (int j = 0; j < 2; ++j) {
            const int grp = w * 2 + j;
            const int row = grp * 8 + rr;
            gld16(kbb + (size_t)(k0 + row) * HD + ci * 8, smK + grp * 1024);
            gld16(vTb + (size_t)row * SEQ + k0 + ci * 8, smV + grp * 1024);
        }
        __syncthreads();

        f32x4 sf[4];
#pragma unroll
        for (int f = 0; f < 4; ++f) {
            const int kr = f * 16 + c;
            const char* kp = smK + kr * 128;
            const short8 bk0 = ld8l(kp + ((quad    ) ^ (kr & 7)) * 16);
            const short8 bk1 = ld8l(kp + ((quad + 4) ^ (kr & 7)) * 16);
            sf[f] = __builtin_amdgcn_mfma_f32_16x16x32_bf16(aq0, bk0, z, 0, 0, 0);
            sf[f] = __builtin_amdgcn_mfma_f32_16x16x32_bf16(aq1, bk1, sf[f], 0, 0, 0);
        }

        if (T == t) {
#pragma unroll
            for (int f = 0; f < 4; ++f) {
                const int key = k0 + f * 16 + c;
#pragma unroll
                for (int r = 0; r < 4; ++r)
                    if (key > q0w + quad * 4 + r) sf[f][r] = -1e30f;
            }
        }

        float p[4][4];
#pragma unroll
        for (int f = 0; f < 4; ++f)
#pragma unroll
            for (int r = 0; r < 4; ++r)
                p[f][r] = __expf(sf[f][r]);
#pragma unroll
        for (int r = 0; r < 4; ++r) {
            lp[r] += (p[0][r] + p[1][r]) + (p[2][r] + p[3][r]);
            uint2 dd;
            dd.x = (unsigned int)bfb(p[0][r]) | ((unsigned int)bfb(p[1][r]) << 16);
            dd.y = (unsigned int)bfb(p[2][r]) | ((unsigned int)bfb(p[3][r]) << 16);
            *(uint2*)&Ps[w][(quad * 4 + r) * 36 + c * 2] = dd;
        }

        const short8 ap0 = ld8l(&Ps[w][c * 36 + quad * 4]);
        const short8 ap1 = ld8l(&Ps[w][c * 36 + 16 + quad * 4]);

#pragma unroll
        for (int f = 0; f < 4; ++f) {
            const int vr = f * 16 + c;
            const char* vp = smV + vr * 128;
            const short8 bv0 = ld8l(vp + ((quad    ) ^ (vr & 7)) * 16);
            const short8 bv1 = ld8l(vp + ((quad + 4) ^ (vr & 7)) * 16);
            f32x4* po = (f == 0) ? &o0 : (f == 1) ? &o1 : (f == 2) ? &o2 : &o3;
            *po = __builtin_amdgcn_mfma_f32_16x16x32_bf16(ap0, bv0, *po, 0, 0, 0);
            *po = __builtin_amdgcn_mfma_f32_16x16x32_bf16(ap1, bv1, *po, 0, 0, 0);
        }
        __syncthreads();
    }

#pragma unroll
    for (int r = 0; r < 4; ++r) {
        float v = lp[r];
        v += __shfl_xor(v, 1, 64);
        v += __shfl_xor(v, 2, 64);
        v += __shfl_xor(v, 4, 64);
        v += __shfl_xor(v, 8, 64);
        lp[r] = v;
    }

    float* ob = Opart + (size_t)stripe * (BATCH * SEQ * HD)
                      + ((size_t)b * SEQ + q0w) * HD;
#pragma unroll
    for (int r = 0; r < 4; ++r) {
        const int row = quad * 4 + r;
        ob[row * HD +  0 + c] = o0[r];
        ob[row * HD + 16 + c] = o1[r];
        ob[row * HD + 32 + c] = o2[r];
        ob[row * HD + 48 + c] = o3[r];
        if (c == 0)
            Lpart[(size_t)stripe * (BATCH * SEQ) + (size_t)b * SEQ + q0w + row] = lp[r];
    }
}

// ---------------------------------------------------------------------------
// normalize v2: out = (sum_s Opart[s]) / (sum_s Lpart[s]), float4-vectorized.
// ---------------------------------------------------------------------------
__global__ __launch_bounds__(256) void normalize_kernel(
    float* __restrict__ out,
    const float* __restrict__ Opart,
    const float* __restrict__ Lpart)
{
    const int idx4 = blockIdx.x * 256 + threadIdx.x;   // float4 index
    const int row  = idx4 >> 4;
    const float4* O4 = (const float4*)Opart;
    float4 s = O4[idx4];
    float  l = Lpart[row];
#pragma unroll
    for (int st = 1; st < NSTRIPE; ++st) {
        const float4 v = O4[(size_t)st * (BATCH * SEQ * HD / 4) + idx4];
        s.x += v.x; s.y += v.y; s.z += v.z; s.w += v.w;
        l += Lpart[(size_t)st * (BATCH * SEQ) + row];
    }
    const float inv = 1.0f / l;
    float4 o; o.x = s.x * inv; o.y = s.y * inv; o.z = s.z * inv; o.w = s.w * inv;
    ((float4*)out)[idx4] = o;
}

// ---------------------------------------------------------------------------
extern "C" void kernel_launch(void* const* d_in, const int* in_sizes, int n_in,
                              void* d_out, int out_size, void* d_ws, size_t ws_size,
                              hipStream_t stream)
{
    (void)in_sizes; (void)n_in; (void)out_size; (void)ws_size;
    const float* x  = (const float*)d_in[0];
    const float* Wk = (const float*)d_in[1];
    const float* Wq = (const float*)d_in[2];
    const float* Wv = (const float*)d_in[3];
    float* out = (float*)d_out;

    const size_t BSH = (size_t)BATCH * SEQ * HD;        // 1,048,576 elems
    __hip_bfloat16* qs = (__hip_bfloat16*)d_ws;         // 2 MB
    __hip_bfloat16* kb = qs + BSH;                      // 2 MB
    __hip_bfloat16* vT = kb + BSH;                      // 2 MB
    __hip_bfloat16* WT = vT + BSH;                      // 384 KB
    float* Opart = (float*)(WT + 192 * EMB);            // 16 MB (4 stripes)
    float* Lpart = Opart + (size_t)NSTRIPE * BSH;       // 256 KB (~23 MB ws)

    prep_w<<<48, 256, 0, stream>>>(Wk, Wq, Wv, WT);
    gemm_proj<<<2 * BATCH * SEQ / 32, 256, 0, stream>>>(x, WT, qs, kb, vT);
    attn_kernel<<<NSTRIPE * BATCH * (SEQ / 64), 256, 0, stream>>>(qs, kb, vT, Opart, Lpart);
    normalize_kernel<<<BATCH * SEQ * HD / 4 / 256, 256, 0, stream>>>(out, Opart, Lpart);
}